// Round 10
// baseline (252.859 us; speedup 1.0000x reference)
//
#include <hip/hip_runtime.h>
#include <cstdint>
#include <cmath>

#define Bn 4096
#define Dn 256
#define On 256

typedef __bf16 v8bf __attribute__((ext_vector_type(8)));
typedef float  v4f  __attribute__((ext_vector_type(4)));
typedef unsigned short us8 __attribute__((ext_vector_type(8)));

__device__ __forceinline__ unsigned short f2bf(float f) {
    // round-to-nearest-even fp32 -> bf16 (inputs are finite normals)
    unsigned int u = __builtin_bit_cast(unsigned int, f);
    unsigned int r = (u + 0x7fffu + ((u >> 16) & 1u)) >> 16;
    return (unsigned short)r;
}

__device__ __forceinline__ void gl_lds16(const void* g, void* l) {
    __builtin_amdgcn_global_load_lds(
        (const __attribute__((address_space(1))) void*)(uintptr_t)g,
        (__attribute__((address_space(3))) void*)(uintptr_t)l, 16, 0, 0);
}

// ---------------------------------------------------------------------------
// Kernel 1: FUSED prep — IDENTICAL to round 6 (proven). Blocks [0,2560):
// build A' = pre-swizzled 16x16x32 MFMA A-operand order of
// (triu(rots,1)+triu^T+diag(scales)) in bf16:
//   A'[o][s][k][lane][j] = A[o][i = s*16+(lane&15)][kcol = k*32+(lane>>4)*8+j]
// 1KB per (o, 16-i-strip s, 32-k-step k). Blocks [2560,2816): x -> bf16.
// ---------------------------------------------------------------------------
__global__ __launch_bounds__(256) void prep(
    const float* __restrict__ scales, const float* __restrict__ rots,
    const float* __restrict__ x, unsigned short* __restrict__ Ap,
    unsigned short* __restrict__ xb) {
    const int bid = blockIdx.x;
    const int tid = threadIdx.x;

    if (bid >= 2560) {                   // ---- cvt_x part: 256 blocks ----
        const int cb = bid - 2560;
#pragma unroll
        for (int s = 0; s < 4; ++s) {
            const int i = cb * 4096 + s * 1024 + tid * 4;
            const float4 v = *(const float4*)(x + i);
            ushort4 u;
            u.x = f2bf(v.x); u.y = f2bf(v.y); u.z = f2bf(v.z); u.w = f2bf(v.w);
            *(ushort4*)(xb + i) = u;
        }
        return;
    }

    // ---- build_A' part: 2560 blocks, one per unordered 64x64 tile pair ----
    static const int TI[10] = {0, 0, 0, 0, 1, 1, 1, 2, 2, 3};
    static const int TJ[10] = {0, 1, 2, 3, 1, 2, 3, 2, 3, 3};
    const int o  = bid / 10;
    const int p  = bid - o * 10;
    const int ti = TI[p], tj = TJ[p];

    __shared__ float t[64][68];          // 16B-aligned rows, padded banks
    const float* src = rots + (size_t)o * Dn * Dn + (size_t)(ti * 64) * Dn + tj * 64;
#pragma unroll
    for (int s = 0; s < 4; ++s) {
        const int idx = s * 256 + tid;
        const int r = idx >> 4, c = (idx & 15) * 4;
        const float4 v = *(const float4*)(src + r * Dn + c);
        *(float4*)&t[r][c] = v;
    }
    __syncthreads();

    // phase U: output tile (ti,tj) -> A' blocks s=ti*4+sl, k=tj*2+kl
#pragma unroll
    for (int it = 0; it < 2; ++it) {
        const int slot = it * 256 + tid;
        const int bk = slot >> 6, L = slot & 63;
        const int quad = L >> 4, frow = L & 15;
        const int sl = bk >> 1, kl = bk & 1;
        const int r = sl * 16 + frow, c = kl * 32 + quad * 8;
        float v[8];
        if (ti == tj) {
#pragma unroll
            for (int q = 0; q < 8; ++q) {
                const int cc = c + q;
                v[q] = (r < cc) ? t[r][cc]
                     : ((r > cc) ? t[cc][r] : scales[o * Dn + ti * 64 + r]);
            }
        } else {
            const float4 a = *(const float4*)&t[r][c];
            const float4 b = *(const float4*)&t[r][c + 4];
            v[0] = a.x; v[1] = a.y; v[2] = a.z; v[3] = a.w;
            v[4] = b.x; v[5] = b.y; v[6] = b.z; v[7] = b.w;
        }
        us8 u;
#pragma unroll
        for (int q = 0; q < 8; ++q) u[q] = f2bf(v[q]);
        const size_t off = ((size_t)((o * 16 + ti * 4 + sl) * 8 + tj * 2 + kl)) * 512 + L * 8;
        *(us8*)(Ap + off) = u;           // 64 consecutive L -> 1KB coalesced
    }

    if (ti != tj) {                      // phase L: mirror tile (tj,ti), transposed
#pragma unroll
        for (int it = 0; it < 2; ++it) {
            const int slot = it * 256 + tid;
            const int bk = slot >> 6, L = slot & 63;
            const int quad = L >> 4, frow = L & 15;
            const int sl = bk >> 1, kl = bk & 1;
            const int r = sl * 16 + frow, c = kl * 32 + quad * 8;
            us8 u;
#pragma unroll
            for (int q = 0; q < 8; ++q) u[q] = f2bf(t[c + q][r]);
            const size_t off = ((size_t)((o * 16 + tj * 4 + sl) * 8 + ti * 2 + kl)) * 512 + L * 8;
            *(us8*)(Ap + off) = u;
        }
    }
}

// ---------------------------------------------------------------------------
// Kernel 2: fused GEMM + norm + bell — the untested design cell:
// (1 o/block, BM=64, 3 waves/SIMD). r8's BM=64 failure was its o-quad L2
// thrash (FETCH 765 MB), NOT the tile size; here the residency-proven
// 1-o decode is kept (extended to 64 btiles: ~2 live o/XCD -> A' L2-resident).
// acc[4][4]=64 AGPR + af 32 + xf 16 + addr => total regs <=168 -> 3 waves/SIMD
// (__launch_bounds__(256,3)); LDS 34 KB -> 3 blocks/CU. 16-MFMA bursts are
// covered by 2 other waves (r7's failure was short bursts at only 2 waves).
// Everything else byte-identical to the proven r6/r9 body: Xs 4 chunks
// [64][64] @128 B row stride + XOR granule swizzle (0-conflict), barrier-free
// K-loop, af ping-pong, r6-verified epilogue mapping, direct out store.
// ---------------------------------------------------------------------------
__global__ __launch_bounds__(256, 3) void fuzzy_main(
    const unsigned short* __restrict__ Ap, const unsigned short* __restrict__ xb,
    const float* __restrict__ cent, const float* __restrict__ bvals,
    float* __restrict__ out) {
    __shared__ __align__(16) unsigned short Xs[4][64 * 64];  // 32 KB
    __shared__ float ssbuf[4][64];                           // 1 KB
    __shared__ float centL[Dn];                              // 1 KB

    const int tid  = threadIdx.x;
    const int lane = tid & 63;
    const int wv   = tid >> 6;
    // grid 16384 = 8 xcd x 64 btile x 32 olow; 1 o per block, o pinned to XCD
    const int Lb = blockIdx.x;
    const int o  = (Lb & 7) * 32 + (Lb >> 9);
    const int b0 = ((Lb >> 3) & 63) * 64;

    centL[tid] = cent[o * Dn + tid];

    const int frow = lane & 15, quad = lane >> 4, f3 = lane & 7;
    const int lr = lane >> 3, ls = lane & 7;
    const int ksw = (ls ^ lr) * 8;       // swizzled source k-offset within chunk

    // stage Xs once: per chunk c, 8 regions of 1KB (8 rows each), 2 per wave.
    // dest = chunk base + reg*1024B + lane*16B (wave-uniform + lane*16) ✓
#pragma unroll
    for (int c = 0; c < 4; ++c)
#pragma unroll
        for (int q = 0; q < 2; ++q) {
            const int row = (wv * 2 + q) * 8 + lr;
            gl_lds16(xb + (size_t)(b0 + row) * Dn + c * 64 + ksw,
                     &Xs[c][row * 64 + ls * 8]);
        }

    const unsigned short* Aw = Ap + (size_t)(o * 16 + wv * 4) * 4096;
    // A-frag for (strip mi, kstep t): Aw + (mi*8 + t)*512 + lane*8 (1KB/frag)

    v4f acc[4][4];
#pragma unroll
    for (int mi = 0; mi < 4; ++mi)
#pragma unroll
        for (int ni = 0; ni < 4; ++ni)
            acc[mi][ni] = v4f{0.f, 0.f, 0.f, 0.f};

    v8bf af[2][4];
#pragma unroll
    for (int mi = 0; mi < 4; ++mi)       // t=0 A-frags: no barrier dependency
        af[0][mi] = *(const v8bf*)(Aw + (size_t)mi * 8 * 512 + lane * 8);

    __syncthreads();   // the ONLY barrier before the epilogue

#pragma unroll
    for (int t = 0; t < 8; ++t) {
        const int cur = t & 1, nxt = cur ^ 1;
        if (t < 7) {
#pragma unroll
            for (int mi = 0; mi < 4; ++mi)
                af[nxt][mi] = *(const v8bf*)(Aw + (size_t)(mi * 8 + t + 1) * 512 + lane * 8);
        }
        v8bf xf[4];
        const int sl = ((t & 1) * 4 + quad) ^ f3;   // proven 0-conflict class
#pragma unroll
        for (int ni = 0; ni < 4; ++ni)
            xf[ni] = *(const v8bf*)&Xs[t >> 1][(ni * 16 + frow) * 64 + sl * 8];
#pragma unroll
        for (int mi = 0; mi < 4; ++mi)
#pragma unroll
            for (int ni = 0; ni < 4; ++ni)
                acc[mi][ni] = __builtin_amdgcn_mfma_f32_16x16x32_bf16(
                    af[cur][mi], xf[ni], acc[mi][ni], 0, 0, 0);
    }

    // epilogue: y = acc + centroid; reduce sum_i y^2 (C/D: col=lane&15=b,
    // row=quad*4+rg=i) — verified rounds 1-9.
    float cv[4][4];
#pragma unroll
    for (int mi = 0; mi < 4; ++mi)
#pragma unroll
        for (int rg = 0; rg < 4; ++rg)
            cv[mi][rg] = centL[wv * 64 + mi * 16 + quad * 4 + rg];
#pragma unroll
    for (int ni = 0; ni < 4; ++ni) {
        float v = 0.f;
#pragma unroll
        for (int mi = 0; mi < 4; ++mi)
#pragma unroll
            for (int rg = 0; rg < 4; ++rg) {
                const float y = acc[mi][ni][rg] + cv[mi][rg];
                v += y * y;
            }
        v += __shfl_xor(v, 16);
        v += __shfl_xor(v, 32);
        if (lane < 16) {
            if (wv == 0) ssbuf[0][ni * 16 + lane] = v;   // avoid init race:
        }
    }
    __syncthreads();   // wave-0 seeds, others accumulate after barrier
    if (wv > 0) {
#pragma unroll
        for (int ni = 0; ni < 4; ++ni) {
            float v = 0.f;
#pragma unroll
            for (int mi = 0; mi < 4; ++mi)
#pragma unroll
                for (int rg = 0; rg < 4; ++rg) {
                    const float y = acc[mi][ni][rg] + cv[mi][rg];
                    v += y * y;
                }
            v += __shfl_xor(v, 16);
            v += __shfl_xor(v, 32);
            if (lane < 16) ssbuf[wv][ni * 16 + lane] = v;
        }
    }
    __syncthreads();
    if (tid < 64) {
        const float ssq = ssbuf[0][tid] + ssbuf[1][tid] + ssbuf[2][tid] + ssbuf[3][tid];
        out[(size_t)(b0 + tid) * On + o] = 1.0f / (1.0f + powf(ssq, bvals[o]));
    }
}

// ---------------------------------------------------------------------------
// Fallback (only if d_ws is too small): exact fp32, slow but correct.
// ---------------------------------------------------------------------------
__global__ void fallback_kernel(const float* __restrict__ x, const float* __restrict__ scales,
                                const float* __restrict__ rots, const float* __restrict__ cent,
                                const float* __restrict__ bvals, float* __restrict__ out) {
    const int b = blockIdx.x * blockDim.x + threadIdx.x;
    const int o = blockIdx.y;
    if (b >= Bn) return;
    const float* R  = rots + (size_t)o * Dn * Dn;
    const float* xv = x + (size_t)b * Dn;
    float ss = 0.f;
    for (int i = 0; i < Dn; ++i) {
        float a = cent[o * Dn + i];
        for (int j = 0; j < Dn; ++j) {
            const float w = (j > i) ? R[i * Dn + j]
                          : ((j < i) ? R[j * Dn + i] : scales[o * Dn + i]);
            a += w * xv[j];
        }
        ss += a * a;
    }
    out[(size_t)b * On + o] = 1.f / (1.f + powf(ss, bvals[o]));
}

extern "C" void kernel_launch(void* const* d_in, const int* in_sizes, int n_in,
                              void* d_out, int out_size, void* d_ws, size_t ws_size,
                              hipStream_t stream) {
    const float* x         = (const float*)d_in[0];
    const float* scales    = (const float*)d_in[1];
    const float* rots      = (const float*)d_in[2];
    const float* centroids = (const float*)d_in[3];
    const float* bvals     = (const float*)d_in[4];
    float* out = (float*)d_out;

    const size_t needA = (size_t)On * Dn * Dn * sizeof(unsigned short); // 33.5 MB
    const size_t needX = (size_t)Bn * Dn * sizeof(unsigned short);      //  2.1 MB

    if (ws_size >= needA + needX) {
        unsigned short* Ap = (unsigned short*)d_ws;
        unsigned short* xb = (unsigned short*)((char*)d_ws + needA);
        prep<<<dim3(2816), 256, 0, stream>>>(scales, rots, x, Ap, xb);
        fuzzy_main<<<dim3(16384), 256, 0, stream>>>(Ap, xb, centroids, bvals, out);
    } else {
        fallback_kernel<<<dim3(Bn / 256, On), 256, 0, stream>>>(x, scales, rots, centroids,
                                                                bvals, out);
    }
}

// Round 11
// 215.035 us; speedup vs baseline: 1.1759x; 1.1759x over previous
//
#include <hip/hip_runtime.h>
#include <cstdint>
#include <cmath>

#define Bn 4096
#define Dn 256
#define On 256

typedef __bf16 v8bf __attribute__((ext_vector_type(8)));
typedef float  v4f  __attribute__((ext_vector_type(4)));
typedef unsigned short us8 __attribute__((ext_vector_type(8)));

__device__ __forceinline__ unsigned short f2bf(float f) {
    // round-to-nearest-even fp32 -> bf16 (inputs are finite normals)
    unsigned int u = __builtin_bit_cast(unsigned int, f);
    unsigned int r = (u + 0x7fffu + ((u >> 16) & 1u)) >> 16;
    return (unsigned short)r;
}

__device__ __forceinline__ void gl_lds16(const void* g, void* l) {
    __builtin_amdgcn_global_load_lds(
        (const __attribute__((address_space(1))) void*)(uintptr_t)g,
        (__attribute__((address_space(3))) void*)(uintptr_t)l, 16, 0, 0);
}

// ---------------------------------------------------------------------------
// Kernel 1: FUSED prep — IDENTICAL to round 6 (proven). Blocks [0,2560):
// build A' = pre-swizzled 16x16x32 MFMA A-operand order of
// (triu(rots,1)+triu^T+diag(scales)) in bf16:
//   A'[o][s][k][lane][j] = A[o][i = s*16+(lane&15)][kcol = k*32+(lane>>4)*8+j]
// 1KB per (o, 16-i-strip s, 32-k-step k). Blocks [2560,2816): x -> bf16.
// ---------------------------------------------------------------------------
__global__ __launch_bounds__(256) void prep(
    const float* __restrict__ scales, const float* __restrict__ rots,
    const float* __restrict__ x, unsigned short* __restrict__ Ap,
    unsigned short* __restrict__ xb) {
    const int bid = blockIdx.x;
    const int tid = threadIdx.x;

    if (bid >= 2560) {                   // ---- cvt_x part: 256 blocks ----
        const int cb = bid - 2560;
#pragma unroll
        for (int s = 0; s < 4; ++s) {
            const int i = cb * 4096 + s * 1024 + tid * 4;
            const float4 v = *(const float4*)(x + i);
            ushort4 u;
            u.x = f2bf(v.x); u.y = f2bf(v.y); u.z = f2bf(v.z); u.w = f2bf(v.w);
            *(ushort4*)(xb + i) = u;
        }
        return;
    }

    // ---- build_A' part: 2560 blocks, one per unordered 64x64 tile pair ----
    static const int TI[10] = {0, 0, 0, 0, 1, 1, 1, 2, 2, 3};
    static const int TJ[10] = {0, 1, 2, 3, 1, 2, 3, 2, 3, 3};
    const int o  = bid / 10;
    const int p  = bid - o * 10;
    const int ti = TI[p], tj = TJ[p];

    __shared__ float t[64][68];          // 16B-aligned rows, padded banks
    const float* src = rots + (size_t)o * Dn * Dn + (size_t)(ti * 64) * Dn + tj * 64;
#pragma unroll
    for (int s = 0; s < 4; ++s) {
        const int idx = s * 256 + tid;
        const int r = idx >> 4, c = (idx & 15) * 4;
        const float4 v = *(const float4*)(src + r * Dn + c);
        *(float4*)&t[r][c] = v;
    }
    __syncthreads();

    // phase U: output tile (ti,tj) -> A' blocks s=ti*4+sl, k=tj*2+kl
#pragma unroll
    for (int it = 0; it < 2; ++it) {
        const int slot = it * 256 + tid;
        const int bk = slot >> 6, L = slot & 63;
        const int quad = L >> 4, frow = L & 15;
        const int sl = bk >> 1, kl = bk & 1;
        const int r = sl * 16 + frow, c = kl * 32 + quad * 8;
        float v[8];
        if (ti == tj) {
#pragma unroll
            for (int q = 0; q < 8; ++q) {
                const int cc = c + q;
                v[q] = (r < cc) ? t[r][cc]
                     : ((r > cc) ? t[cc][r] : scales[o * Dn + ti * 64 + r]);
            }
        } else {
            const float4 a = *(const float4*)&t[r][c];
            const float4 b = *(const float4*)&t[r][c + 4];
            v[0] = a.x; v[1] = a.y; v[2] = a.z; v[3] = a.w;
            v[4] = b.x; v[5] = b.y; v[6] = b.z; v[7] = b.w;
        }
        us8 u;
#pragma unroll
        for (int q = 0; q < 8; ++q) u[q] = f2bf(v[q]);
        const size_t off = ((size_t)((o * 16 + ti * 4 + sl) * 8 + tj * 2 + kl)) * 512 + L * 8;
        *(us8*)(Ap + off) = u;           // 64 consecutive L -> 1KB coalesced
    }

    if (ti != tj) {                      // phase L: mirror tile (tj,ti), transposed
#pragma unroll
        for (int it = 0; it < 2; ++it) {
            const int slot = it * 256 + tid;
            const int bk = slot >> 6, L = slot & 63;
            const int quad = L >> 4, frow = L & 15;
            const int sl = bk >> 1, kl = bk & 1;
            const int r = sl * 16 + frow, c = kl * 32 + quad * 8;
            us8 u;
#pragma unroll
            for (int q = 0; q < 8; ++q) u[q] = f2bf(t[c + q][r]);
            const size_t off = ((size_t)((o * 16 + tj * 4 + sl) * 8 + ti * 2 + kl)) * 512 + L * 8;
            *(us8*)(Ap + off) = u;
        }
    }
}

// ---------------------------------------------------------------------------
// Kernel 2: fused GEMM + norm + bell — A-RESIDENT design. One block owns one
// o for a HALF of the batch (32 btiles of 64): each wave loads its entire
// 64-i A'-strip into REGISTERS ONCE (32 frags = 128 VGPR; A read once from
// HBM: 67 MB total vs r6's 1.07 GB of L2 re-reads), then loops 32 btiles:
// stage next Xs into the other LDS buffer (proven 4x[64][64] 128B-stride
// layout), 8 ksteps x 16 MFMA (2480-cyc burst per wave covers the staging
// latency completely -> the per-iter barrier drain is free), epilogue
// partials into parity-double-buffered ssbuf (no timing assumptions).
// Budget: af 128 + xf 16 + cv 16 + misc VGPR + acc 64 AGPR ~ 250/wave,
// LDS 2x32 KB + small -> 2 blocks/CU, 2 waves/SIMD.
// Grid 512 = 8 XCD x 32 o x 2 bhalf (o pinned to XCD, 4 live o/XCD).
// ---------------------------------------------------------------------------
__global__ __launch_bounds__(256, 2) void fuzzy_main(
    const unsigned short* __restrict__ Ap, const unsigned short* __restrict__ xb,
    const float* __restrict__ cent, const float* __restrict__ bvals,
    float* __restrict__ out) {
    __shared__ __align__(16) unsigned short Xs[2][4][64 * 64];  // 64 KB dbuf
    __shared__ float ssbuf[2][4][64];                           // parity dbuf
    __shared__ float centL[Dn];

    const int tid  = threadIdx.x;
    const int lane = tid & 63;
    const int wv   = tid >> 6;
    // grid 512 = 8 xcd x 32 olow x 2 bhalf
    const int Lb = blockIdx.x;
    const int o     = (Lb & 7) * 32 + ((Lb >> 3) & 31);
    const int bhalf = Lb >> 8;

    centL[tid] = cent[o * Dn + tid];

    const int frow = lane & 15, quad = lane >> 4, f3 = lane & 7;
    const int lr = lane >> 3, ls = lane & 7;
    const int ksw = (ls ^ lr) * 8;       // swizzled source k-offset within chunk

    // ---- load this wave's ENTIRE A'-strip into registers (once) ----
    const unsigned short* Aw = Ap + (size_t)(o * 16 + wv * 4) * 4096;
    v8bf af[4][8];                       // [mi][t]  128 VGPRs
#pragma unroll
    for (int mi = 0; mi < 4; ++mi)
#pragma unroll
        for (int t = 0; t < 8; ++t)
            af[mi][t] = *(const v8bf*)(Aw + (size_t)(mi * 8 + t) * 512 + lane * 8);

    float cv[4][4];
#pragma unroll
    for (int mi = 0; mi < 4; ++mi)       // centroid values for this wave's i's
#pragma unroll
        for (int rg = 0; rg < 4; ++rg)
            cv[mi][rg] = cent[o * Dn + wv * 64 + mi * 16 + quad * 4 + rg];

    // ---- stage btile 0 into buffer 0 ----
    {
        const int b0 = bhalf * 2048;
#pragma unroll
        for (int c = 0; c < 4; ++c)
#pragma unroll
            for (int q = 0; q < 2; ++q) {
                const int row = (wv * 2 + q) * 8 + lr;
                gl_lds16(xb + (size_t)(b0 + row) * Dn + c * 64 + ksw,
                         &Xs[0][c][row * 64 + ls * 8]);
            }
    }
    __syncthreads();

    for (int it = 0; it < 32; ++it) {
        const int buf = it & 1;
        const int b0  = bhalf * 2048 + it * 64;
        if (it < 31) {                   // prefetch next btile into other buffer
            const int nb0 = b0 + 64;
#pragma unroll
            for (int c = 0; c < 4; ++c)
#pragma unroll
                for (int q = 0; q < 2; ++q) {
                    const int row = (wv * 2 + q) * 8 + lr;
                    gl_lds16(xb + (size_t)(nb0 + row) * Dn + c * 64 + ksw,
                             &Xs[buf ^ 1][c][row * 64 + ls * 8]);
                }
        }

        v4f acc[4][4];
#pragma unroll
        for (int mi = 0; mi < 4; ++mi)
#pragma unroll
            for (int ni = 0; ni < 4; ++ni)
                acc[mi][ni] = v4f{0.f, 0.f, 0.f, 0.f};

#pragma unroll
        for (int t = 0; t < 8; ++t) {
            v8bf xf[4];
            const int sl = ((t & 1) * 4 + quad) ^ f3;   // proven 0-conflict class
#pragma unroll
            for (int ni = 0; ni < 4; ++ni)
                xf[ni] = *(const v8bf*)&Xs[buf][t >> 1][(ni * 16 + frow) * 64 + sl * 8];
#pragma unroll
            for (int mi = 0; mi < 4; ++mi)
#pragma unroll
                for (int ni = 0; ni < 4; ++ni)
                    acc[mi][ni] = __builtin_amdgcn_mfma_f32_16x16x32_bf16(
                        af[mi][t], xf[ni], acc[mi][ni], 0, 0, 0);
        }

        // epilogue: partial sum_i y^2 for this wave's 64 i (C/D map verified
        // r1-r10: col=lane&15=b, row=quad*4+rg=i); parity-buffered ssbuf.
#pragma unroll
        for (int ni = 0; ni < 4; ++ni) {
            float v = 0.f;
#pragma unroll
            for (int mi = 0; mi < 4; ++mi)
#pragma unroll
                for (int rg = 0; rg < 4; ++rg) {
                    const float y = acc[mi][ni][rg] + cv[mi][rg];
                    v += y * y;
                }
            v += __shfl_xor(v, 16);
            v += __shfl_xor(v, 32);
            if (lane < 16) ssbuf[buf][wv][ni * 16 + lane] = v;
        }
        __syncthreads();   // staging of buf^1 done (covered by MFMA burst),
                           // ssbuf[buf] visible; next iter writes ssbuf[buf^1]
        if (tid < 64) {
            const float ssq = ssbuf[buf][0][tid] + ssbuf[buf][1][tid] +
                              ssbuf[buf][2][tid] + ssbuf[buf][3][tid];
            out[(size_t)(b0 + tid) * On + o] = 1.0f / (1.0f + powf(ssq, bvals[o]));
        }
    }
}

// ---------------------------------------------------------------------------
// Fallback (only if d_ws is too small): exact fp32, slow but correct.
// ---------------------------------------------------------------------------
__global__ void fallback_kernel(const float* __restrict__ x, const float* __restrict__ scales,
                                const float* __restrict__ rots, const float* __restrict__ cent,
                                const float* __restrict__ bvals, float* __restrict__ out) {
    const int b = blockIdx.x * blockDim.x + threadIdx.x;
    const int o = blockIdx.y;
    if (b >= Bn) return;
    const float* R  = rots + (size_t)o * Dn * Dn;
    const float* xv = x + (size_t)b * Dn;
    float ss = 0.f;
    for (int i = 0; i < Dn; ++i) {
        float a = cent[o * Dn + i];
        for (int j = 0; j < Dn; ++j) {
            const float w = (j > i) ? R[i * Dn + j]
                          : ((j < i) ? R[j * Dn + i] : scales[o * Dn + i]);
            a += w * xv[j];
        }
        ss += a * a;
    }
    out[(size_t)b * On + o] = 1.f / (1.f + powf(ss, bvals[o]));
}

extern "C" void kernel_launch(void* const* d_in, const int* in_sizes, int n_in,
                              void* d_out, int out_size, void* d_ws, size_t ws_size,
                              hipStream_t stream) {
    const float* x         = (const float*)d_in[0];
    const float* scales    = (const float*)d_in[1];
    const float* rots      = (const float*)d_in[2];
    const float* centroids = (const float*)d_in[3];
    const float* bvals     = (const float*)d_in[4];
    float* out = (float*)d_out;

    const size_t needA = (size_t)On * Dn * Dn * sizeof(unsigned short); // 33.5 MB
    const size_t needX = (size_t)Bn * Dn * sizeof(unsigned short);      //  2.1 MB

    if (ws_size >= needA + needX) {
        unsigned short* Ap = (unsigned short*)d_ws;
        unsigned short* xb = (unsigned short*)((char*)d_ws + needA);
        prep<<<dim3(2816), 256, 0, stream>>>(scales, rots, x, Ap, xb);
        fuzzy_main<<<dim3(512), 256, 0, stream>>>(Ap, xb, centroids, bvals, out);
    } else {
        fallback_kernel<<<dim3(Bn / 256, On), 256, 0, stream>>>(x, scales, rots, centroids,
                                                                bvals, out);
    }
}